// Round 2
// baseline (703.697 us; speedup 1.0000x reference)
//
#include <hip/hip_runtime.h>
#include <hip/hip_bf16.h>

// Problem dims (fixed by setup_inputs): L=2, B=32, S=2048, D=1024. All floats f32.
constexpr int LAY = 2;
constexpr int BB  = 32;
constexpr int SS  = 2048;
constexpr int DD  = 1024;

typedef unsigned short u16;
typedef short  short8  __attribute__((ext_vector_type(8)));
typedef u16    u16x8   __attribute__((ext_vector_type(8)));
typedef float  floatx4 __attribute__((ext_vector_type(4)));

__device__ inline float bf2f(u16 u) {
    union { unsigned int i; float f; } v; v.i = ((unsigned int)u) << 16; return v.f;
}
__device__ inline u16 f2bf_rn(float f) {
    union { float f; unsigned int i; } v; v.f = f;
    unsigned int x = v.i;
    return (u16)((x + 0x7FFFu + ((x >> 16) & 1u)) >> 16);
}

// Branch-free fast tanh: 1 - 2*rcp(exp(2x)+1).
// x=+inf -> exp=inf -> rcp=0 -> 1; x=-inf -> exp=0 -> rcp(1)=1 -> -1. ~1e-6 abs err.
__device__ __forceinline__ float fast_tanh(float x) {
    float e = __expf(x + x);
    return 1.0f - 2.0f * __builtin_amdgcn_rcpf(e + 1.0f);
}

__device__ __forceinline__ void gload_lds16(const u16* g, u16* l) {
    __builtin_amdgcn_global_load_lds(
        (const __attribute__((address_space(1))) void*)g,
        (__attribute__((address_space(3))) void*)l, 16, 0, 0);
}

// ---------------------------------------------------------------------------
// enc f32 -> bf16 (rn). Grid-stride: 2048 blocks x 256 thr x 16 iters x 8 elems.
__global__ __launch_bounds__(256) void convert_enc(const float* __restrict__ enc,
                                                   u16* __restrict__ encbf) {
    size_t gid = (size_t)blockIdx.x * 256 + threadIdx.x;   // 0..524287
    #pragma unroll 4
    for (int it = 0; it < 16; ++it) {
        size_t i = (it * 524288ull + gid) * 8;
        floatx4 v0 = *reinterpret_cast<const floatx4*>(enc + i);
        floatx4 v1 = *reinterpret_cast<const floatx4*>(enc + i + 4);
        u16x8 r;
        #pragma unroll
        for (int j = 0; j < 4; ++j) { r[j] = f2bf_rn(v0[j]); r[4 + j] = f2bf_rn(v1[j]); }
        *reinterpret_cast<u16x8*>(encbf + i) = r;
    }
}

// W_enc f32 [K][N] -> wT bf16 [N][K]. Thread handles (n, 8 consecutive k).
__global__ __launch_bounds__(256) void transpose_wenc(const float* __restrict__ W,
                                                      u16* __restrict__ wT) {
    int gid = blockIdx.x * 256 + threadIdx.x;   // 0..131071
    int n = gid & 1023, c = gid >> 10;          // c: 0..127
    int k0 = c * 8;
    u16x8 r;
    #pragma unroll
    for (int j = 0; j < 8; ++j) r[j] = f2bf_rn(W[(size_t)(k0 + j) * DD + n]);
    *reinterpret_cast<u16x8*>(&wT[(size_t)n * DD + k0]) = r;
}

// ---------------------------------------------------------------------------
// dec_proj[b][col] += sum_{e in kc-chunk} h[e] * W_dec[e][col]  (+b_dec on kc==0)
__global__ __launch_bounds__(256) void dec_proj_kernel(
    const float* __restrict__ dec_hidden, const float* __restrict__ W_dec,
    const float* __restrict__ b_dec, float* __restrict__ dec_proj) {
    int kc = blockIdx.x, cb = blockIdx.y, b = blockIdx.z, t = threadIdx.x;
    int col = cb * 256 + t;
    const float* h = dec_hidden + (LAY - 1) * BB * DD + b * DD + kc * 256;
    const float* Wp = W_dec + (size_t)kc * 256 * DD + col;
    float a0 = 0.f, a1 = 0.f, a2 = 0.f, a3 = 0.f;
    for (int e = 0; e < 256; e += 4) {
        a0 += h[e + 0] * Wp[(size_t)(e + 0) * DD];
        a1 += h[e + 1] * Wp[(size_t)(e + 1) * DD];
        a2 += h[e + 2] * Wp[(size_t)(e + 2) * DD];
        a3 += h[e + 3] * Wp[(size_t)(e + 3) * DD];
    }
    float v = (a0 + a1) + (a2 + a3);
    if (kc == 0) v += b_dec[col];
    atomicAdd(&dec_proj[b * DD + col], v);
}

// ---------------------------------------------------------------------------
// Fused: E = enc @ W_enc;  scores[r] += sum_n tanh(E[r][n] + dec_proj[b][n] + b_enc[n]) * w_att[n]
// 128x128 tile, BK=64. T3-min 2-phase pipeline: double-buffered LDS, issue
// STAGE(next) BEFORE compute(cur); the single __syncthreads() per kt (implicit
// vmcnt(0)+lgkmcnt(0) drain) then waits on loads that already had a full
// compute phase (~600 cyc of ds_read+MFMA) in flight -> latency hidden.
// XOR-swizzled LDS via pre-swizzled per-lane SOURCE addresses (DMA dest is
// wave-uniform base + lane*16, can't be swizzled directly).
// XCD swizzle (T1): f%8 = XCD owns contiguous swz chunk, n-fastest decode.
__global__ __launch_bounds__(256) void score_gemm_bf(
    const u16* __restrict__ enc,      // [M][K] bf16 row-major
    const u16* __restrict__ wT,       // [N][K] bf16 row-major
    const float* __restrict__ dec_proj,
    const float* __restrict__ b_enc, const float* __restrict__ w_att,
    float* __restrict__ scores) {
    __shared__ u16 As[2][128 * 64];
    __shared__ u16 Bs[2][128 * 64];

    const int tid  = threadIdx.x;
    const int f    = blockIdx.x;                 // 0..4095
    const int swz  = ((f & 7) << 9) | (f >> 3);  // bijective (4096 % 8 == 0)
    const int bm   = swz >> 3;                   // 0..511
    const int bn   = swz & 7;                    // 0..7
    const int row0 = bm * 128, col0 = bn * 128;
    const int lane = tid & 63, w = tid >> 6;
    const int wm   = w >> 1,  wn = w & 1;
    const int quad = lane >> 4, l16 = lane & 15;

    // staging: wave w, issue i covers rows [i*32 + w*8, +8)
    // lane l -> local row l>>3, LDS kchunk slot l&7, global kchunk (l&7)^(l>>3)
    const int srow = w * 8 + (lane >> 3);
    const int scol = (((lane & 7) ^ (lane >> 3)) * 8);

    auto stage = [&](int buf, int k0) {
        #pragma unroll
        for (int i = 0; i < 4; ++i) {
            gload_lds16(&enc[(size_t)(row0 + i * 32 + srow) * DD + k0 + scol],
                        &As[buf][(i * 32 + w * 8) * 64]);
            gload_lds16(&wT [(size_t)(col0 + i * 32 + srow) * DD + k0 + scol],
                        &Bs[buf][(i * 32 + w * 8) * 64]);
        }
    };

    floatx4 acc[4][4];
    #pragma unroll
    for (int i = 0; i < 4; ++i)
        #pragma unroll
        for (int j = 0; j < 4; ++j)
            acc[i][j] = (floatx4){0.f, 0.f, 0.f, 0.f};

    // Hoist epilogue operand loads above the main loop (latency hidden under GEMM).
    const int bIdx = row0 / SS;
    const float* dp = dec_proj + bIdx * DD;
    float cvec[4], wvv[4];
    #pragma unroll
    for (int tn = 0; tn < 4; ++tn) {
        int n = col0 + wn * 64 + tn * 16 + l16;
        cvec[tn] = dp[n] + b_enc[n];
        wvv[tn]  = w_att[n];
    }

    auto compute = [&](int buf) {
        #pragma unroll
        for (int ks = 0; ks < 2; ++ks) {
            short8 a[4], b[4];
            #pragma unroll
            for (int tm = 0; tm < 4; ++tm) {
                int r = wm * 64 + tm * 16 + l16;
                int kcs = (ks * 4 + quad) ^ (l16 & 7);
                a[tm] = *reinterpret_cast<const short8*>(&As[buf][r * 64 + kcs * 8]);
            }
            #pragma unroll
            for (int tn = 0; tn < 4; ++tn) {
                int r = wn * 64 + tn * 16 + l16;
                int kcs = (ks * 4 + quad) ^ (l16 & 7);
                b[tn] = *reinterpret_cast<const short8*>(&Bs[buf][r * 64 + kcs * 8]);
            }
            #pragma unroll
            for (int tm = 0; tm < 4; ++tm)
                #pragma unroll
                for (int tn = 0; tn < 4; ++tn)
                    acc[tm][tn] = __builtin_amdgcn_mfma_f32_16x16x32_bf16(
                        a[tm], b[tn], acc[tm][tn], 0, 0, 0);
        }
    };

    // prologue: stage kt=0 into buf 0; drain; then 2-phase steady state.
    stage(0, 0);
    __syncthreads();
    for (int kt = 0; kt < 16; kt += 2) {
        if (kt + 1 < 16) stage(1, (kt + 1) * 64);   // prefetch next tile
        compute(0);
        __syncthreads();                            // drains vmcnt (prefetch landed)
        if (kt + 2 < 16) stage(0, (kt + 2) * 64);
        compute(1);
        __syncthreads();
    }

    // Epilogue: tanh + dot(w_att) + per-row reduce + atomicAdd
    // C/D layout (m89/m91-verified): col = lane&15, row = quad*4 + reg
    #pragma unroll
    for (int tm = 0; tm < 4; ++tm) {
        float rs0 = 0.f, rs1 = 0.f, rs2 = 0.f, rs3 = 0.f;
        #pragma unroll
        for (int tn = 0; tn < 4; ++tn) {
            rs0 += fast_tanh(acc[tm][tn][0] + cvec[tn]) * wvv[tn];
            rs1 += fast_tanh(acc[tm][tn][1] + cvec[tn]) * wvv[tn];
            rs2 += fast_tanh(acc[tm][tn][2] + cvec[tn]) * wvv[tn];
            rs3 += fast_tanh(acc[tm][tn][3] + cvec[tn]) * wvv[tn];
        }
        #pragma unroll
        for (int off = 1; off < 16; off <<= 1) {
            rs0 += __shfl_xor(rs0, off, 64);
            rs1 += __shfl_xor(rs1, off, 64);
            rs2 += __shfl_xor(rs2, off, 64);
            rs3 += __shfl_xor(rs3, off, 64);
        }
        if (l16 == 0) {
            int rbase = row0 + wm * 64 + tm * 16 + quad * 4;
            atomicAdd(&scores[rbase + 0], rs0);
            atomicAdd(&scores[rbase + 1], rs1);
            atomicAdd(&scores[rbase + 2], rs2);
            atomicAdd(&scores[rbase + 3], rs3);
        }
    }
}

// ---------------------------------------------------------------------------
// Masked softmax over S per b. b_att omitted (shift-invariant).
__global__ __launch_bounds__(256) void softmax_kernel(
    const float* __restrict__ scores, const int* __restrict__ mask,
    float* __restrict__ attn_out) {
    int b = blockIdx.x, t = threadIdx.x;
    const float* srow = scores + b * SS;
    const int*   mrow = mask + b * SS;
    float vals[8];
    float vmax = -1e30f;
    #pragma unroll
    for (int i = 0; i < 8; ++i) {
        int s = i * 256 + t;
        float v = (mrow[s] == 0) ? -1e10f : srow[s];
        vals[i] = v;
        vmax = fmaxf(vmax, v);
    }
    #pragma unroll
    for (int off = 32; off >= 1; off >>= 1) vmax = fmaxf(vmax, __shfl_xor(vmax, off, 64));
    __shared__ float sm[4];
    if ((t & 63) == 0) sm[t >> 6] = vmax;
    __syncthreads();
    vmax = fmaxf(fmaxf(sm[0], sm[1]), fmaxf(sm[2], sm[3]));
    float sum = 0.f;
    #pragma unroll
    for (int i = 0; i < 8; ++i) { vals[i] = __expf(vals[i] - vmax); sum += vals[i]; }
    #pragma unroll
    for (int off = 32; off >= 1; off >>= 1) sum += __shfl_xor(sum, off, 64);
    __shared__ float ssum[4];
    if ((t & 63) == 0) ssum[t >> 6] = sum;
    __syncthreads();
    sum = ssum[0] + ssum[1] + ssum[2] + ssum[3];
    float inv = 1.f / sum;
    #pragma unroll
    for (int i = 0; i < 8; ++i) attn_out[b * SS + i * 256 + t] = vals[i] * inv;
}

// ---------------------------------------------------------------------------
// ctx[b][d..d+7] += sum_s attn[b][s] * encbf[b][s][d..d+7]
// 512 blocks (16 s-chunks x 32 b), 16 B/lane loads, 2 s-rows in flight per block.
__global__ __launch_bounds__(256) void context_bf(
    const float* __restrict__ attn, const u16* __restrict__ encbf,
    float* __restrict__ ctx) {
    int scb = blockIdx.x;   // 0..15
    int b   = blockIdx.y;   // 0..31
    int t   = threadIdx.x;
    int d   = (t & 127) * 8;            // 8 bf16 per thread -> 128 thr cover a row
    int sh  = t >> 7;                   // waves 0,1: even s; waves 2,3: odd s
    const float* ar  = attn + b * SS + scb * 128;
    const u16*  base = encbf + ((size_t)b * SS + scb * 128) * DD + d;
    float a[8];
    #pragma unroll
    for (int j = 0; j < 8; ++j) a[j] = 0.f;
    #pragma unroll 4
    for (int so = 0; so < 128; so += 2) {
        int s = so + sh;
        u16x8 v = *reinterpret_cast<const u16x8*>(base + (size_t)s * DD);
        float w = ar[s];
        #pragma unroll
        for (int j = 0; j < 8; ++j) a[j] += w * bf2f(v[j]);
    }
    #pragma unroll
    for (int j = 0; j < 8; ++j) atomicAdd(&ctx[b * DD + d + j], a[j]);
}

// ---------------------------------------------------------------------------
extern "C" void kernel_launch(void* const* d_in, const int* in_sizes, int n_in,
                              void* d_out, int out_size, void* d_ws, size_t ws_size,
                              hipStream_t stream) {
    const float* dec_hidden = (const float*)d_in[0];
    const float* enc        = (const float*)d_in[1];
    const int*   mask       = (const int*)d_in[2];
    const float* W_dec      = (const float*)d_in[3];
    const float* b_dec      = (const float*)d_in[4];
    const float* W_enc      = (const float*)d_in[5];
    const float* b_enc      = (const float*)d_in[6];
    const float* w_att      = (const float*)d_in[7];
    // d_in[8] (b_att): uniform shift into softmax -> no effect, omitted.

    float* out = (float*)d_out;               // [0,32768) context ; [32768,98304) attn
    float* ws  = (float*)d_ws;
    float* dec_proj = ws;                     // 32768 f32
    float* scores   = ws + 32768;             // 65536 f32
    u16*   wT       = (u16*)(ws + 98304);     // 1M bf16 (2 MB)
    u16*   encbf    = (u16*)(ws + 622592);    // 64M bf16 (128 MB)
    float* attn     = out + 32768;

    hipMemsetAsync(ws, 0, 98304 * sizeof(float), stream);
    hipMemsetAsync(out, 0, 32768 * sizeof(float), stream);

    convert_enc<<<2048, 256, 0, stream>>>(enc, encbf);
    transpose_wenc<<<512, 256, 0, stream>>>(W_enc, wT);
    dec_proj_kernel<<<dim3(4, 4, 32), 256, 0, stream>>>(dec_hidden, W_dec, b_dec, dec_proj);
    score_gemm_bf<<<4096, 256, 0, stream>>>(encbf, wT, dec_proj, b_enc, w_att, scores);
    softmax_kernel<<<32, 256, 0, stream>>>(scores, mask, attn);
    context_bf<<<dim3(16, 32), 256, 0, stream>>>(attn, encbf, out);
}

// Round 4
// 665.106 us; speedup vs baseline: 1.0580x; 1.0580x over previous
//
#include <hip/hip_runtime.h>
#include <hip/hip_bf16.h>

// Problem dims (fixed by setup_inputs): L=2, B=32, S=2048, D=1024. All floats f32.
constexpr int LAY = 2;
constexpr int BB  = 32;
constexpr int SS  = 2048;
constexpr int DD  = 1024;

typedef unsigned short u16;
typedef short  short8  __attribute__((ext_vector_type(8)));
typedef u16    u16x8   __attribute__((ext_vector_type(8)));
typedef float  floatx4 __attribute__((ext_vector_type(4)));

__device__ inline float bf2f(u16 u) {
    union { unsigned int i; float f; } v; v.i = ((unsigned int)u) << 16; return v.f;
}
__device__ inline u16 f2bf_rn(float f) {
    union { float f; unsigned int i; } v; v.f = f;
    unsigned int x = v.i;
    return (u16)((x + 0x7FFFu + ((x >> 16) & 1u)) >> 16);
}

// Branch-free fast tanh: 1 - 2*rcp(exp(2x)+1).
__device__ __forceinline__ float fast_tanh(float x) {
    float e = __expf(x + x);
    return 1.0f - 2.0f * __builtin_amdgcn_rcpf(e + 1.0f);
}

__device__ __forceinline__ void gload_lds16(const u16* g, u16* l) {
    __builtin_amdgcn_global_load_lds(
        (const __attribute__((address_space(1))) void*)g,
        (__attribute__((address_space(3))) void*)l, 16, 0, 0);
}

// ---------------------------------------------------------------------------
// enc f32 -> bf16 (rn). Grid-stride: 2048 blocks x 256 thr x 16 iters x 8 elems.
__global__ __launch_bounds__(256) void convert_enc(const float* __restrict__ enc,
                                                   u16* __restrict__ encbf) {
    size_t gid = (size_t)blockIdx.x * 256 + threadIdx.x;   // 0..524287
    #pragma unroll 4
    for (int it = 0; it < 16; ++it) {
        size_t i = (it * 524288ull + gid) * 8;
        floatx4 v0 = *reinterpret_cast<const floatx4*>(enc + i);
        floatx4 v1 = *reinterpret_cast<const floatx4*>(enc + i + 4);
        u16x8 r;
        #pragma unroll
        for (int j = 0; j < 4; ++j) { r[j] = f2bf_rn(v0[j]); r[4 + j] = f2bf_rn(v1[j]); }
        *reinterpret_cast<u16x8*>(encbf + i) = r;
    }
}

// W_enc f32 [K][N] -> wT bf16 [N][K]. Thread handles (n, 8 consecutive k).
__global__ __launch_bounds__(256) void transpose_wenc(const float* __restrict__ W,
                                                      u16* __restrict__ wT) {
    int gid = blockIdx.x * 256 + threadIdx.x;   // 0..131071
    int n = gid & 1023, c = gid >> 10;          // c: 0..127
    int k0 = c * 8;
    u16x8 r;
    #pragma unroll
    for (int j = 0; j < 8; ++j) r[j] = f2bf_rn(W[(size_t)(k0 + j) * DD + n]);
    *reinterpret_cast<u16x8*>(&wT[(size_t)n * DD + k0]) = r;
}

// ---------------------------------------------------------------------------
// dec_proj[b][col] += sum_{e in kc-chunk} h[e] * W_dec[e][col]  (+b_dec on kc==0)
__global__ __launch_bounds__(256) void dec_proj_kernel(
    const float* __restrict__ dec_hidden, const float* __restrict__ W_dec,
    const float* __restrict__ b_dec, float* __restrict__ dec_proj) {
    int kc = blockIdx.x, cb = blockIdx.y, b = blockIdx.z, t = threadIdx.x;
    int col = cb * 256 + t;
    const float* h = dec_hidden + (LAY - 1) * BB * DD + b * DD + kc * 256;
    const float* Wp = W_dec + (size_t)kc * 256 * DD + col;
    float a0 = 0.f, a1 = 0.f, a2 = 0.f, a3 = 0.f;
    for (int e = 0; e < 256; e += 4) {
        a0 += h[e + 0] * Wp[(size_t)(e + 0) * DD];
        a1 += h[e + 1] * Wp[(size_t)(e + 1) * DD];
        a2 += h[e + 2] * Wp[(size_t)(e + 2) * DD];
        a3 += h[e + 3] * Wp[(size_t)(e + 3) * DD];
    }
    float v = (a0 + a1) + (a2 + a3);
    if (kc == 0) v += b_dec[col];
    atomicAdd(&dec_proj[b * DD + col], v);
}

// ---------------------------------------------------------------------------
// Fused: E = enc @ W_enc;  scores[r] += sum_n tanh(E[r][n]+dec_proj[b][n]+b_enc[n])*w_att[n]
// 256x256 tile, BK=64, 512 thr = 8 waves (2M x 4N), per-wave output 128x64.
// Phase-split schedule: per K-tile two {ds_read frags -> setprio MFMA} phases;
// raw s_barrier mid-tile crossed by in-flight staging; tile boundary is a
// plain __syncthreads() (full drain + barrier).
// Race ledger: stage(buf^1, kt+1) only issues after the boundary barrier that
// closed ALL waves' reads of buf^1 (tile kt-1). __syncthreads at the boundary
// drains every wave's own DMA (vmcnt) before the join => tile kt+1 fully
// landed before any wave reads it.
// LDS XOR swizzle (T2) via pre-swizzled SOURCE addresses (DMA dest is linear).
// XCD swizzle (T1): 1024 blocks, f%8 = XCD owns contiguous 128-chunk.
__global__ __launch_bounds__(512, 2) void score_gemm_bf(
    const u16* __restrict__ enc,      // [M][K] bf16 row-major
    const u16* __restrict__ wT,       // [N][K] bf16 row-major
    const float* __restrict__ dec_proj,
    const float* __restrict__ b_enc, const float* __restrict__ w_att,
    float* __restrict__ scores) {
    __shared__ u16 As[2][256 * 64];   // 32 KB each
    __shared__ u16 Bs[2][256 * 64];   // total 128 KB

    const int tid  = threadIdx.x;
    const int f    = blockIdx.x;                 // 0..1023
    const int swz  = ((f & 7) << 7) | (f >> 3);  // bijective (1024 % 8 == 0)
    const int bm   = swz >> 2;                   // 0..255
    const int bn   = swz & 3;                    // 0..3
    const int row0 = bm * 256, col0 = bn * 256;
    const int lane = tid & 63, w = tid >> 6;     // w: 0..7
    const int wm   = w >> 2,  wn = w & 3;        // 2 x 4 wave grid
    const int quad = lane >> 4, l16 = lane & 15;

    // staging: wave w, issue i covers rows [i*64 + w*8, +8)
    // lane l -> local row l>>3, LDS kchunk slot l&7, global kchunk (l&7)^(l>>3)
    const int srow = w * 8 + (lane >> 3);
    const int scol = (((lane & 7) ^ (lane >> 3)) * 8);

    auto stageA = [&](int buf, int k0) {
        #pragma unroll
        for (int i = 0; i < 4; ++i)
            gload_lds16(&enc[(size_t)(row0 + i * 64 + srow) * DD + k0 + scol],
                        &As[buf][(i * 64 + w * 8) * 64]);
    };
    auto stageB = [&](int buf, int k0) {
        #pragma unroll
        for (int i = 0; i < 4; ++i)
            gload_lds16(&wT[(size_t)(col0 + i * 64 + srow) * DD + k0 + scol],
                        &Bs[buf][(i * 64 + w * 8) * 64]);
    };

    floatx4 acc[8][4];
    #pragma unroll
    for (int i = 0; i < 8; ++i)
        #pragma unroll
        for (int j = 0; j < 4; ++j)
            acc[i][j] = (floatx4){0.f, 0.f, 0.f, 0.f};

    // Hoist epilogue operands (latency hidden under GEMM).
    const int bIdx = row0 / SS;
    const float* dp = dec_proj + bIdx * DD;
    float cvec[4], wvv[4];
    #pragma unroll
    for (int tn = 0; tn < 4; ++tn) {
        int n = col0 + wn * 64 + tn * 16 + l16;
        cvec[tn] = dp[n] + b_enc[n];
        wvv[tn]  = w_att[n];
    }

    // one ks-phase: 12 ds_read_b128 + 32 MFMA under setprio
    auto phase = [&](int buf, int ks) {
        short8 a[8], b[4];
        const int kcs = (ks * 4 + quad) ^ (l16 & 7);
        #pragma unroll
        for (int m = 0; m < 8; ++m) {
            int r = wm * 128 + m * 16 + l16;
            a[m] = *reinterpret_cast<const short8*>(&As[buf][r * 64 + kcs * 8]);
        }
        #pragma unroll
        for (int n = 0; n < 4; ++n) {
            int r = wn * 64 + n * 16 + l16;
            b[n] = *reinterpret_cast<const short8*>(&Bs[buf][r * 64 + kcs * 8]);
        }
        __builtin_amdgcn_s_setprio(1);
        #pragma unroll
        for (int m = 0; m < 8; ++m)
            #pragma unroll
            for (int n = 0; n < 4; ++n)
                acc[m][n] = __builtin_amdgcn_mfma_f32_16x16x32_bf16(
                    a[m], b[n], acc[m][n], 0, 0, 0);
        __builtin_amdgcn_s_setprio(0);
    };

    #define MID_BAR  do { __builtin_amdgcn_s_barrier(); \
                          __builtin_amdgcn_sched_barrier(0); } while (0)

    // prologue: stage tile 0 into buf0, full drain.
    stageA(0, 0); stageB(0, 0);
    __syncthreads();

    for (int kt = 0; kt < 16; kt += 2) {
        // ---- tile kt from buf0; prefetch kt+1 into buf1 (issue-early) ----
        if (kt + 1 < 16) stageA(1, (kt + 1) * 64);
        phase(0, 0);
        MID_BAR;                       // crossed by in-flight staging loads
        if (kt + 1 < 16) stageB(1, (kt + 1) * 64);
        phase(0, 1);
        __syncthreads();               // own kt+1 DMA drained + all waves joined
        // ---- tile kt+1 from buf1; prefetch kt+2 into buf0 ----
        if (kt + 2 < 16) stageA(0, (kt + 2) * 64);
        phase(1, 0);
        MID_BAR;
        if (kt + 2 < 16) stageB(0, (kt + 2) * 64);
        phase(1, 1);
        __syncthreads();
    }
    #undef MID_BAR

    // Epilogue: tanh + dot(w_att) + per-row reduce + atomicAdd
    // C/D layout (m89/m91-verified): col = lane&15, row = quad*4 + reg
    #pragma unroll
    for (int tm = 0; tm < 8; ++tm) {
        float rs0 = 0.f, rs1 = 0.f, rs2 = 0.f, rs3 = 0.f;
        #pragma unroll
        for (int tn = 0; tn < 4; ++tn) {
            rs0 += fast_tanh(acc[tm][tn][0] + cvec[tn]) * wvv[tn];
            rs1 += fast_tanh(acc[tm][tn][1] + cvec[tn]) * wvv[tn];
            rs2 += fast_tanh(acc[tm][tn][2] + cvec[tn]) * wvv[tn];
            rs3 += fast_tanh(acc[tm][tn][3] + cvec[tn]) * wvv[tn];
        }
        #pragma unroll
        for (int off = 1; off < 16; off <<= 1) {
            rs0 += __shfl_xor(rs0, off, 64);
            rs1 += __shfl_xor(rs1, off, 64);
            rs2 += __shfl_xor(rs2, off, 64);
            rs3 += __shfl_xor(rs3, off, 64);
        }
        if (l16 == 0) {
            int rbase = row0 + wm * 128 + tm * 16 + quad * 4;
            atomicAdd(&scores[rbase + 0], rs0);
            atomicAdd(&scores[rbase + 1], rs1);
            atomicAdd(&scores[rbase + 2], rs2);
            atomicAdd(&scores[rbase + 3], rs3);
        }
    }
}

// ---------------------------------------------------------------------------
// Masked softmax over S per b. b_att omitted (shift-invariant).
__global__ __launch_bounds__(256) void softmax_kernel(
    const float* __restrict__ scores, const int* __restrict__ mask,
    float* __restrict__ attn_out) {
    int b = blockIdx.x, t = threadIdx.x;
    const float* srow = scores + b * SS;
    const int*   mrow = mask + b * SS;
    float vals[8];
    float vmax = -1e30f;
    #pragma unroll
    for (int i = 0; i < 8; ++i) {
        int s = i * 256 + t;
        float v = (mrow[s] == 0) ? -1e10f : srow[s];
        vals[i] = v;
        vmax = fmaxf(vmax, v);
    }
    #pragma unroll
    for (int off = 32; off >= 1; off >>= 1) vmax = fmaxf(vmax, __shfl_xor(vmax, off, 64));
    __shared__ float sm[4];
    if ((t & 63) == 0) sm[t >> 6] = vmax;
    __syncthreads();
    vmax = fmaxf(fmaxf(sm[0], sm[1]), fmaxf(sm[2], sm[3]));
    float sum = 0.f;
    #pragma unroll
    for (int i = 0; i < 8; ++i) { vals[i] = __expf(vals[i] - vmax); sum += vals[i]; }
    #pragma unroll
    for (int off = 32; off >= 1; off >>= 1) sum += __shfl_xor(sum, off, 64);
    __shared__ float ssum[4];
    if ((t & 63) == 0) ssum[t >> 6] = sum;
    __syncthreads();
    sum = ssum[0] + ssum[1] + ssum[2] + ssum[3];
    float inv = 1.f / sum;
    #pragma unroll
    for (int i = 0; i < 8; ++i) attn_out[b * SS + i * 256 + t] = vals[i] * inv;
}

// ---------------------------------------------------------------------------
// ctx[b][d..d+7] += sum_s attn[b][s] * encbf[b][s][d..d+7]
__global__ __launch_bounds__(256) void context_bf(
    const float* __restrict__ attn, const u16* __restrict__ encbf,
    float* __restrict__ ctx) {
    int scb = blockIdx.x;   // 0..15
    int b   = blockIdx.y;   // 0..31
    int t   = threadIdx.x;
    int d   = (t & 127) * 8;            // 8 bf16 per thread -> 128 thr cover a row
    int sh  = t >> 7;                   // waves 0,1: even s; waves 2,3: odd s
    const float* ar  = attn + b * SS + scb * 128;
    const u16*  base = encbf + ((size_t)b * SS + scb * 128) * DD + d;
    float a[8];
    #pragma unroll
    for (int j = 0; j < 8; ++j) a[j] = 0.f;
    #pragma unroll 4
    for (int so = 0; so < 128; so += 2) {
        int s = so + sh;
        u16x8 v = *reinterpret_cast<const u16x8*>(base + (size_t)s * DD);
        float w = ar[s];
        #pragma unroll
        for (int j = 0; j < 8; ++j) a[j] += w * bf2f(v[j]);
    }
    #pragma unroll
    for (int j = 0; j < 8; ++j) atomicAdd(&ctx[b * DD + d + j], a[j]);
}

// ---------------------------------------------------------------------------
extern "C" void kernel_launch(void* const* d_in, const int* in_sizes, int n_in,
                              void* d_out, int out_size, void* d_ws, size_t ws_size,
                              hipStream_t stream) {
    const float* dec_hidden = (const float*)d_in[0];
    const float* enc        = (const float*)d_in[1];
    const int*   mask       = (const int*)d_in[2];
    const float* W_dec      = (const float*)d_in[3];
    const float* b_dec      = (const float*)d_in[4];
    const float* W_enc      = (const float*)d_in[5];
    const float* b_enc      = (const float*)d_in[6];
    const float* w_att      = (const float*)d_in[7];
    // d_in[8] (b_att): uniform shift into softmax -> no effect, omitted.

    float* out = (float*)d_out;               // [0,32768) context ; [32768,98304) attn
    float* ws  = (float*)d_ws;
    float* dec_proj = ws;                     // 32768 f32
    float* scores   = ws + 32768;             // 65536 f32
    u16*   wT       = (u16*)(ws + 98304);     // 1M bf16 (2 MB)
    u16*   encbf    = (u16*)(ws + 622592);    // 64M bf16 (128 MB)
    float* attn     = out + 32768;

    hipMemsetAsync(ws, 0, 98304 * sizeof(float), stream);
    hipMemsetAsync(out, 0, 32768 * sizeof(float), stream);

    convert_enc<<<2048, 256, 0, stream>>>(enc, encbf);
    transpose_wenc<<<512, 256, 0, stream>>>(W_enc, wT);
    dec_proj_kernel<<<dim3(4, 4, 32), 256, 0, stream>>>(dec_hidden, W_dec, b_dec, dec_proj);
    score_gemm_bf<<<1024, 512, 0, stream>>>(encbf, wT, dec_proj, b_enc, w_att, scores);
    softmax_kernel<<<32, 256, 0, stream>>>(scores, mask, attn);
    context_bf<<<dim3(16, 32), 256, 0, stream>>>(attn, encbf, out);
}